// Round 2
// baseline (1030.583 us; speedup 1.0000x reference)
//
#include <hip/hip_runtime.h>
#include <hip/hip_bf16.h>

// ---------------------------------------------------------------------------
// TelechatAttention fused forward (fp32 in/out, bf16 MFMA internally):
//   q = hs@Wq (RoPE), kv = hs@Wkv (RoPE on k), causal GQA attention,
//   out = ctx@Wd + b + residual
// Inputs/outputs fp32 per reference; hidden/weights converted once to bf16.
// ---------------------------------------------------------------------------

#define BB   2
#define SS   2048
#define HH   4096
#define NHH  32
#define HDD  128
#define KVHH 8

typedef unsigned short u16;
typedef __attribute__((ext_vector_type(8))) short  short8;   // 8 bf16 = 4 VGPR
typedef __attribute__((ext_vector_type(4))) float  floatx4;  // MFMA C/D

#define AS1 __attribute__((address_space(1)))
#define AS3 __attribute__((address_space(3)))

__device__ __forceinline__ void gll16(const void* g, void* l) {
    __builtin_amdgcn_global_load_lds((const AS1 unsigned int*)g,
                                     (AS3 unsigned int*)l, 16, 0, 0);
}
__device__ __forceinline__ float b2f(u16 x) {
    union { unsigned int u; float f; } c; c.u = ((unsigned int)x) << 16; return c.f;
}
__device__ __forceinline__ u16 f2b(float f) {
    union { float f; unsigned int u; } c; c.f = f;
    unsigned int r = 0x7FFFu + ((c.u >> 16) & 1u);
    return (u16)((c.u + r) >> 16);
}

// ---------------------------------------------------------------------------
// fp32 -> bf16 bulk convert (vectorized float4 loads)
// ---------------------------------------------------------------------------
__global__ __launch_bounds__(256)
void cvt_kernel(const float* __restrict__ X, u16* __restrict__ Y, int n4) {
    int i = blockIdx.x * 256 + threadIdx.x;
    if (i >= n4) return;
    float4 v = *(const float4*)(X + (size_t)i * 4);
    size_t o = (size_t)i * 4;
    Y[o + 0] = f2b(v.x); Y[o + 1] = f2b(v.y);
    Y[o + 2] = f2b(v.z); Y[o + 3] = f2b(v.w);
}

// ---------------------------------------------------------------------------
// RoPE cos/sin table: seq_len=8192>=S so ntk_alpha=1, mscale=1, base=10000.
// ---------------------------------------------------------------------------
__global__ __launch_bounds__(256) void rope_table(float* __restrict__ ct,
                                                  float* __restrict__ st) {
    int idx = blockIdx.x * 256 + threadIdx.x;
    if (idx >= SS * 64) return;
    int s = idx >> 6, i = idx & 63;
    double inv = pow(10000.0, -(double)(2 * i) / 128.0);
    double f = (double)s * inv;
    ct[idx] = (float)cos(f);
    st[idx] = (float)sin(f);
}

// ---------------------------------------------------------------------------
// 64x64 tiled transpose + fp32->bf16: W (R x C fp32) -> WT (C x R bf16)
// ---------------------------------------------------------------------------
__global__ __launch_bounds__(256) void wt_kernel(const float* __restrict__ W,
                                                 u16* __restrict__ WT,
                                                 int R, int C) {
    __shared__ u16 t[64 * 65];
    int tcols = C >> 6;
    int ty = blockIdx.x / tcols, tx = blockIdx.x % tcols;
    int r0 = ty * 64, c0 = tx * 64;
    for (int idx = threadIdx.x; idx < 4096; idx += 256) {
        int r = idx >> 6, c = idx & 63;
        t[r * 65 + c] = f2b(W[(size_t)(r0 + r) * C + c0 + c]);
    }
    __syncthreads();
    for (int idx = threadIdx.x; idx < 4096; idx += 256) {
        int c = idx >> 6, r = idx & 63;
        WT[(size_t)(c0 + c) * R + r0 + r] = t[r * 65 + c];
    }
}

// ---------------------------------------------------------------------------
// GEMM: C[M,N] = A[M,K] @ BT[N,K]^T  (bf16 in, fp32 acc)
// m97 structure: 128x128 tile, BK=32, 4 waves (2x2 of 64x64), 16 MFMA +
// 8 ds_read_b128 per K-step, global_load_lds width=16 staging.
// Output: bf16 to C if Cf==null, else fp32 to Cf with +bias[col]+resid.
// ---------------------------------------------------------------------------
__global__ __launch_bounds__(256, 2)
void gemm_bt(const u16* __restrict__ A, const u16* __restrict__ BT,
             u16* __restrict__ C, float* __restrict__ Cf,
             int M, int N, int K,
             const float* __restrict__ bias, const float* __restrict__ resid) {
    __shared__ u16 sA[128 * 32];   // [m][k], row stride 32
    __shared__ u16 sB[128 * 32];   // [n][k]
    const int tid = threadIdx.x;
    const int wave = tid >> 6, lane = tid & 63;
    const int m0 = blockIdx.y * 128, n0 = blockIdx.x * 128;
    const int wm = (wave >> 1) * 64, wn = (wave & 1) * 64;
    const int srow = lane >> 2, scol = (lane & 3) * 8;  // staging: 16 rows/call
    const int frow = lane & 15, fquad = lane >> 4;
    const int fk = fquad * 8;

    const floatx4 fz = {0.f, 0.f, 0.f, 0.f};
    floatx4 acc[4][4];
#pragma unroll
    for (int i = 0; i < 4; ++i)
#pragma unroll
        for (int j = 0; j < 4; ++j) acc[i][j] = fz;

    for (int kt = 0; kt < K; kt += 32) {
#pragma unroll
        for (int j = 0; j < 2; ++j) {
            int rb = (wave + j * 4) * 16;  // wave-uniform row base
            gll16(A  + (size_t)(m0 + rb + srow) * K + kt + scol, &sA[rb * 32]);
            gll16(BT + (size_t)(n0 + rb + srow) * K + kt + scol, &sB[rb * 32]);
        }
        __syncthreads();
        short8 af[4];
#pragma unroll
        for (int i = 0; i < 4; ++i)
            af[i] = *(const short8*)&sA[(wm + i * 16 + frow) * 32 + fk];
#pragma unroll
        for (int jn = 0; jn < 4; ++jn) {
            short8 bfr = *(const short8*)&sB[(wn + jn * 16 + frow) * 32 + fk];
#pragma unroll
            for (int i = 0; i < 4; ++i)
                acc[i][jn] = __builtin_amdgcn_mfma_f32_16x16x32_bf16(
                    af[i], bfr, acc[i][jn], 0, 0, 0);
        }
        __syncthreads();
    }
    // epilogue: C layout row=(quad*4+r), col=lane&15
#pragma unroll
    for (int i = 0; i < 4; ++i) {
#pragma unroll
        for (int jn = 0; jn < 4; ++jn) {
            int col = n0 + wn + jn * 16 + frow;
            float bv = bias ? bias[col] : 0.f;
#pragma unroll
            for (int r = 0; r < 4; ++r) {
                int row = m0 + wm + i * 16 + fquad * 4 + r;
                float v = acc[i][jn][r] + bv;
                if (Cf) {
                    if (resid) v += resid[(size_t)row * N + col];
                    Cf[(size_t)row * N + col] = v;
                } else {
                    C[(size_t)row * N + col] = f2b(v);
                }
            }
        }
    }
}

// ---------------------------------------------------------------------------
// RoPE apply (in place, bf16): rows [0,B*S*NH) = Q rows (128 elems);
// rows beyond = K rows inside KV (256-elem rows, first 128 = K).
// One wave per row; lane d pairs (d, d+64).
// ---------------------------------------------------------------------------
__global__ __launch_bounds__(256)
void rope_apply(u16* __restrict__ Qb, u16* __restrict__ KVb,
                const float* __restrict__ ct, const float* __restrict__ st) {
    int gid = blockIdx.x * 256 + threadIdx.x;
    int row = gid >> 6, d = gid & 63;
    const int nq = BB * SS * NHH;
    u16* p;
    int s;
    if (row < nq) {
        s = (row / NHH) % SS;
        p = Qb + (size_t)row * HDD;
    } else {
        int r2 = row - nq;
        s = (r2 / KVHH) % SS;
        p = KVb + (size_t)r2 * 256;
    }
    float c = ct[s * 64 + d], sn = st[s * 64 + d];
    float x0 = b2f(p[d]), x1 = b2f(p[d + 64]);
    p[d]      = f2b(x0 * c - x1 * sn);
    p[d + 64] = f2b(x1 * c + x0 * sn);
}

// ---------------------------------------------------------------------------
// V transpose: KV[b,s,kvh, 128+d] -> VT[(b*KVH+kvh), d, s]  (for PV B-frags)
// ---------------------------------------------------------------------------
__global__ __launch_bounds__(256)
void vt_kernel(const u16* __restrict__ KVb, u16* __restrict__ VT) {
    __shared__ u16 t[64 * 130];
    int bid = blockIdx.x;
    int bk = bid >> 5;            // b*KVH + kvh
    int s0 = (bid & 31) * 64;
    int b = bk >> 3, kvh = bk & 7;
    for (int idx = threadIdx.x; idx < 64 * 128; idx += 256) {
        int si = idx >> 7, d = idx & 127;
        t[si * 130 + d] =
            KVb[((size_t)((b * SS + s0 + si) * KVHH + kvh)) * 256 + 128 + d];
    }
    __syncthreads();
    for (int idx = threadIdx.x; idx < 64 * 128; idx += 256) {
        int d = idx >> 6, sj = idx & 63;
        VT[((size_t)(bk * HDD + d)) * SS + s0 + sj] = t[sj * 130 + d];
    }
}

// ---------------------------------------------------------------------------
// Fused causal GQA flash attention (bf16 in/out, fp32 softmax state).
// Block = 4 waves, 128-q tile (wave owns 32 q rows), 64-key tiles, HD=128.
// Online softmax in C-frag registers (row reductions = 4 XOR shuffles within
// each 16-lane quad). P round-trips through LDS (bf16, stride 72).
// CTX written over Q (alias-safe: block writes only the slice it alone read).
// ---------------------------------------------------------------------------
__global__ __launch_bounds__(256, 2)
void attn(const u16* __restrict__ Q, const u16* __restrict__ KV,
          const u16* __restrict__ VT, u16* __restrict__ CTX) {
    __shared__ u16 sK[64 * 128];    // [key][d]
    __shared__ u16 sVT[128 * 64];   // [d][key]
    __shared__ u16 sQP[128 * 128];  // Q tile (stride 128), later P (stride 72)

    const int tid = threadIdx.x;
    const int wave = tid >> 6, lane = tid & 63;
    const int frow = lane & 15, fquad = lane >> 4;
    const int bid = blockIdx.x;          // ((b*16 + qt)*32 + h)
    const int h = bid & 31;
    const int qt = (bid >> 5) & 15;
    const int b = bid >> 9;
    const int kvh = h >> 2;
    const int q0 = qt * 128;

    // ---- stage Q tile (128 rows x 128 d) ----
    {
        const int srow4 = lane >> 4, scol16 = (lane & 15) * 8;
#pragma unroll
        for (int j = 0; j < 8; ++j) {
            int rb = (j * 4 + wave) * 4;
            gll16(Q + ((size_t)((b * SS + q0 + rb + srow4) * NHH + h)) * HDD + scol16,
                  &sQP[rb * 128]);
        }
    }
    __syncthreads();
    short8 qf[2][4];
#pragma unroll
    for (int mi = 0; mi < 2; ++mi)
#pragma unroll
        for (int ds = 0; ds < 4; ++ds)
            qf[mi][ds] = *(const short8*)
                &sQP[(wave * 32 + mi * 16 + frow) * 128 + ds * 32 + fquad * 8];

    const floatx4 fz = {0.f, 0.f, 0.f, 0.f};
    floatx4 o[2][8];
#pragma unroll
    for (int mi = 0; mi < 2; ++mi)
#pragma unroll
        for (int dn = 0; dn < 8; ++dn) o[mi][dn] = fz;
    float mrow[2][4], lrow[2][4];
#pragma unroll
    for (int mi = 0; mi < 2; ++mi)
#pragma unroll
        for (int r = 0; r < 4; ++r) { mrow[mi][r] = -1e30f; lrow[mi][r] = 0.f; }

    const float scale = 0.08838834764831845f;  // 1/sqrt(128)
    const int nt = 2 * (qt + 1);
    for (int t = 0; t < nt; ++t) {
        const int k0 = t * 64;
        // ---- stage K (64x128) and VT (128x64) ----
        {
            int srow4 = lane >> 4, scol16 = (lane & 15) * 8;
#pragma unroll
            for (int j = 0; j < 4; ++j) {
                int rb = (j * 4 + wave) * 4;
                gll16(KV + ((size_t)((b * SS + k0 + rb + srow4) * KVHH + kvh)) * 256 + scol16,
                      &sK[rb * 128]);
            }
            int srow8 = lane >> 3, scol8 = (lane & 7) * 8;
#pragma unroll
            for (int j = 0; j < 4; ++j) {
                int rb = (j * 4 + wave) * 8;
                gll16(VT + ((size_t)((b * KVHH + kvh) * HDD + rb + srow8)) * SS + k0 + scol8,
                      &sVT[rb * 64]);
            }
        }
        __syncthreads();  // drains vmcnt (and tile-0: wave's Q frag reads done)

        // ---- S = Q K^T : per wave 32 MFMAs ----
        floatx4 sc[2][4];
#pragma unroll
        for (int mi = 0; mi < 2; ++mi)
#pragma unroll
            for (int ni = 0; ni < 4; ++ni) sc[mi][ni] = fz;
#pragma unroll
        for (int ds = 0; ds < 4; ++ds) {
#pragma unroll
            for (int ni = 0; ni < 4; ++ni) {
                short8 kf = *(const short8*)
                    &sK[(ni * 16 + frow) * 128 + ds * 32 + fquad * 8];
                sc[0][ni] = __builtin_amdgcn_mfma_f32_16x16x32_bf16(
                    qf[0][ds], kf, sc[0][ni], 0, 0, 0);
                sc[1][ni] = __builtin_amdgcn_mfma_f32_16x16x32_bf16(
                    qf[1][ds], kf, sc[1][ni], 0, 0, 0);
            }
        }

        // ---- online softmax ----
        const bool dgt = (t >= 2 * qt);  // diagonal tile needs element mask
#pragma unroll
        for (int mi = 0; mi < 2; ++mi) {
#pragma unroll
            for (int r = 0; r < 4; ++r) {
                int qg = q0 + wave * 32 + mi * 16 + fquad * 4 + r;
                float mx = -1e30f;
#pragma unroll
                for (int ni = 0; ni < 4; ++ni) {
                    float v = sc[mi][ni][r] * scale;
                    if (dgt) {
                        int kg = k0 + ni * 16 + frow;
                        if (kg > qg) v = -1e30f;
                    }
                    sc[mi][ni][r] = v;
                    mx = fmaxf(mx, v);
                }
                mx = fmaxf(mx, __shfl_xor(mx, 1));
                mx = fmaxf(mx, __shfl_xor(mx, 2));
                mx = fmaxf(mx, __shfl_xor(mx, 4));
                mx = fmaxf(mx, __shfl_xor(mx, 8));
                float mold = mrow[mi][r];
                float mnew = fmaxf(mold, mx);
                float alpha = __expf(mold - mnew);
                mrow[mi][r] = mnew;
                float rs = 0.f;
#pragma unroll
                for (int ni = 0; ni < 4; ++ni) {
                    float pv = __expf(sc[mi][ni][r] - mnew);
                    sc[mi][ni][r] = pv;
                    rs += pv;
                }
                rs += __shfl_xor(rs, 1);
                rs += __shfl_xor(rs, 2);
                rs += __shfl_xor(rs, 4);
                rs += __shfl_xor(rs, 8);
                lrow[mi][r] = lrow[mi][r] * alpha + rs;
#pragma unroll
                for (int dn = 0; dn < 8; ++dn) o[mi][dn][r] *= alpha;
            }
        }

        // ---- P -> LDS (bf16, stride 72) ----
#pragma unroll
        for (int mi = 0; mi < 2; ++mi)
#pragma unroll
            for (int ni = 0; ni < 4; ++ni)
#pragma unroll
                for (int r = 0; r < 4; ++r)
                    sQP[(wave * 32 + mi * 16 + fquad * 4 + r) * 72 + ni * 16 + frow] =
                        f2b(sc[mi][ni][r]);
        __syncthreads();

        // ---- O += P V : per wave 32 MFMAs ----
#pragma unroll
        for (int ks = 0; ks < 2; ++ks) {
            short8 pf0 = *(const short8*)
                &sQP[(wave * 32 + frow) * 72 + ks * 32 + fquad * 8];
            short8 pf1 = *(const short8*)
                &sQP[(wave * 32 + 16 + frow) * 72 + ks * 32 + fquad * 8];
#pragma unroll
            for (int dn = 0; dn < 8; ++dn) {
                short8 vf = *(const short8*)
                    &sVT[(dn * 16 + frow) * 64 + ks * 32 + fquad * 8];
                o[0][dn] = __builtin_amdgcn_mfma_f32_16x16x32_bf16(pf0, vf, o[0][dn], 0, 0, 0);
                o[1][dn] = __builtin_amdgcn_mfma_f32_16x16x32_bf16(pf1, vf, o[1][dn], 0, 0, 0);
            }
        }
        __syncthreads();  // before next staging overwrites sK/sVT/P
    }

    // ---- epilogue: ctx = O / l ----
#pragma unroll
    for (int mi = 0; mi < 2; ++mi) {
#pragma unroll
        for (int r = 0; r < 4; ++r) {
            float inv = 1.f / lrow[mi][r];
            int qg = q0 + wave * 32 + mi * 16 + fquad * 4 + r;
            size_t base = ((size_t)(b * SS + qg) * NHH + h) * HDD;
#pragma unroll
            for (int dn = 0; dn < 8; ++dn)
                CTX[base + dn * 16 + frow] = f2b(o[mi][dn][r] * inv);
        }
    }
}

// ---------------------------------------------------------------------------
// Launch. ws layout (121 MB total; fp32 inputs, bf16 intermediates):
//   [0,32M)    hsb  (bf16 hidden)
//   [32,64M)   Qb   (also CTX, alias-safe)
//   [64,80M)   KVb
//   [80,112M)  T1   (transposed bf16 weight scratch, reused 3x)
//   [112,120M) VTb
//   [120,121M) cos/sin tables (fp32)
// ---------------------------------------------------------------------------
extern "C" void kernel_launch(void* const* d_in, const int* in_sizes, int n_in,
                              void* d_out, int out_size, void* d_ws, size_t ws_size,
                              hipStream_t stream) {
    const float* hidden = (const float*)d_in[0];
    const float* resid  = (const float*)d_in[1];
    // d_in[2] = attention_mask (causal triu k=1) — reconstructed analytically
    const float* Wq  = (const float*)d_in[3];
    const float* Wkv = (const float*)d_in[4];
    const float* Wd  = (const float*)d_in[5];
    const float* bd  = (const float*)d_in[6];
    float* out = (float*)d_out;

    char* ws = (char*)d_ws;
    u16*   hsb = (u16*)(ws);
    u16*   Qb  = (u16*)(ws + ((size_t)32 << 20));
    u16*   KVb = (u16*)(ws + ((size_t)64 << 20));
    u16*   T1  = (u16*)(ws + ((size_t)80 << 20));
    u16*   VTb = (u16*)(ws + ((size_t)112 << 20));
    float* ct  = (float*)(ws + ((size_t)120 << 20));
    float* st  = (float*)(ws + ((size_t)120 << 20) + ((size_t)512 << 10));

    const int M = BB * SS;  // 4096

    rope_table<<<512, 256, 0, stream>>>(ct, st);
    cvt_kernel<<<(M * HH / 4 + 255) / 256, 256, 0, stream>>>(hidden, hsb, M * HH / 4);

    wt_kernel<<<4096, 256, 0, stream>>>(Wq, T1, HH, HH);
    gemm_bt<<<dim3(32, 32), 256, 0, stream>>>(hsb, T1, Qb, nullptr, M, HH, HH,
                                              nullptr, nullptr);
    wt_kernel<<<2048, 256, 0, stream>>>(Wkv, T1, HH, 2 * KVHH * HDD);
    gemm_bt<<<dim3(16, 32), 256, 0, stream>>>(hsb, T1, KVb, nullptr,
                                              M, 2 * KVHH * HDD, HH,
                                              nullptr, nullptr);

    rope_apply<<<(BB * SS * (NHH + KVHH) * 64) / 256, 256, 0, stream>>>(Qb, KVb, ct, st);
    vt_kernel<<<BB * KVHH * (SS / 64), 256, 0, stream>>>(KVb, VTb);

    attn<<<BB * 16 * NHH, 256, 0, stream>>>(Qb, KVb, VTb, /*CTX=*/Qb);

    wt_kernel<<<4096, 256, 0, stream>>>(Wd, T1, HH, HH);
    gemm_bt<<<dim3(32, 32), 256, 0, stream>>>(Qb, T1, nullptr, out, M, HH, HH,
                                              bd, resid);
}

// Round 3
// 1003.586 us; speedup vs baseline: 1.0269x; 1.0269x over previous
//
#include <hip/hip_runtime.h>
#include <hip/hip_bf16.h>

// ---------------------------------------------------------------------------
// TelechatAttention fused forward (fp32 in/out, bf16 MFMA internally):
//   q = hs@Wq (RoPE), kv = hs@Wkv (RoPE on k), causal GQA attention,
//   out = ctx@Wd + b + residual
// ---------------------------------------------------------------------------

#define BB   2
#define SS   2048
#define HH   4096
#define NHH  32
#define HDD  128
#define KVHH 8

typedef unsigned short u16;
typedef __attribute__((ext_vector_type(8))) short  short8;   // 8 bf16 = 4 VGPR
typedef __attribute__((ext_vector_type(4))) float  floatx4;  // MFMA C/D

#define AS1 __attribute__((address_space(1)))
#define AS3 __attribute__((address_space(3)))

__device__ __forceinline__ void gll16(const void* g, void* l) {
    __builtin_amdgcn_global_load_lds((const AS1 unsigned int*)g,
                                     (AS3 unsigned int*)l, 16, 0, 0);
}
__device__ __forceinline__ float b2f(u16 x) {
    union { unsigned int u; float f; } c; c.u = ((unsigned int)x) << 16; return c.f;
}
__device__ __forceinline__ u16 f2b(float f) {
    union { float f; unsigned int u; } c; c.f = f;
    unsigned int r = 0x7FFFu + ((c.u >> 16) & 1u);
    return (u16)((c.u + r) >> 16);
}

// ---------------------------------------------------------------------------
// fp32 -> bf16 bulk convert (vectorized float4 loads)
// ---------------------------------------------------------------------------
__global__ __launch_bounds__(256)
void cvt_kernel(const float* __restrict__ X, u16* __restrict__ Y, int n4) {
    int i = blockIdx.x * 256 + threadIdx.x;
    if (i >= n4) return;
    float4 v = *(const float4*)(X + (size_t)i * 4);
    size_t o = (size_t)i * 4;
    Y[o + 0] = f2b(v.x); Y[o + 1] = f2b(v.y);
    Y[o + 2] = f2b(v.z); Y[o + 3] = f2b(v.w);
}

// ---------------------------------------------------------------------------
// RoPE cos/sin table: seq_len=8192>=S so ntk_alpha=1, mscale=1, base=10000.
// ---------------------------------------------------------------------------
__global__ __launch_bounds__(256) void rope_table(float* __restrict__ ct,
                                                  float* __restrict__ st) {
    int idx = blockIdx.x * 256 + threadIdx.x;
    if (idx >= SS * 64) return;
    int s = idx >> 6, i = idx & 63;
    double inv = pow(10000.0, -(double)(2 * i) / 128.0);
    double f = (double)s * inv;
    ct[idx] = (float)cos(f);
    st[idx] = (float)sin(f);
}

// ---------------------------------------------------------------------------
// 64x64 tiled transpose + fp32->bf16: W (R x C fp32) -> WT (C x R bf16)
// ---------------------------------------------------------------------------
__global__ __launch_bounds__(256) void wt_kernel(const float* __restrict__ W,
                                                 u16* __restrict__ WT,
                                                 int R, int C) {
    __shared__ u16 t[64 * 65];
    int tcols = C >> 6;
    int ty = blockIdx.x / tcols, tx = blockIdx.x % tcols;
    int r0 = ty * 64, c0 = tx * 64;
    for (int idx = threadIdx.x; idx < 4096; idx += 256) {
        int r = idx >> 6, c = idx & 63;
        t[r * 65 + c] = f2b(W[(size_t)(r0 + r) * C + c0 + c]);
    }
    __syncthreads();
    for (int idx = threadIdx.x; idx < 4096; idx += 256) {
        int c = idx >> 6, r = idx & 63;
        WT[(size_t)(c0 + c) * R + r0 + r] = t[r * 65 + c];
    }
}

// ---------------------------------------------------------------------------
// GEMM: C[M,N] = A[M,K] @ BT[N,K]^T  (bf16 in, fp32 acc) — m97 structure.
// Output: bf16 to C if Cf==null, else fp32 to Cf with +bias[col]+resid.
// ---------------------------------------------------------------------------
__global__ __launch_bounds__(256, 2)
void gemm_bt(const u16* __restrict__ A, const u16* __restrict__ BT,
             u16* __restrict__ C, float* __restrict__ Cf,
             int M, int N, int K,
             const float* __restrict__ bias, const float* __restrict__ resid) {
    __shared__ u16 sA[128 * 32];   // [m][k], row stride 32
    __shared__ u16 sB[128 * 32];   // [n][k]
    const int tid = threadIdx.x;
    const int wave = tid >> 6, lane = tid & 63;
    const int m0 = blockIdx.y * 128, n0 = blockIdx.x * 128;
    const int wm = (wave >> 1) * 64, wn = (wave & 1) * 64;
    const int srow = lane >> 2, scol = (lane & 3) * 8;  // staging: 16 rows/call
    const int frow = lane & 15, fquad = lane >> 4;
    const int fk = fquad * 8;

    const floatx4 fz = {0.f, 0.f, 0.f, 0.f};
    floatx4 acc[4][4];
#pragma unroll
    for (int i = 0; i < 4; ++i)
#pragma unroll
        for (int j = 0; j < 4; ++j) acc[i][j] = fz;

    for (int kt = 0; kt < K; kt += 32) {
#pragma unroll
        for (int j = 0; j < 2; ++j) {
            int rb = (wave + j * 4) * 16;  // wave-uniform row base
            gll16(A  + (size_t)(m0 + rb + srow) * K + kt + scol, &sA[rb * 32]);
            gll16(BT + (size_t)(n0 + rb + srow) * K + kt + scol, &sB[rb * 32]);
        }
        __syncthreads();
        short8 af[4];
#pragma unroll
        for (int i = 0; i < 4; ++i)
            af[i] = *(const short8*)&sA[(wm + i * 16 + frow) * 32 + fk];
#pragma unroll
        for (int jn = 0; jn < 4; ++jn) {
            short8 bfr = *(const short8*)&sB[(wn + jn * 16 + frow) * 32 + fk];
#pragma unroll
            for (int i = 0; i < 4; ++i)
                acc[i][jn] = __builtin_amdgcn_mfma_f32_16x16x32_bf16(
                    af[i], bfr, acc[i][jn], 0, 0, 0);
        }
        __syncthreads();
    }
    // epilogue: C layout row=(quad*4+r), col=lane&15
#pragma unroll
    for (int i = 0; i < 4; ++i) {
#pragma unroll
        for (int jn = 0; jn < 4; ++jn) {
            int col = n0 + wn + jn * 16 + frow;
            float bv = bias ? bias[col] : 0.f;
#pragma unroll
            for (int r = 0; r < 4; ++r) {
                int row = m0 + wm + i * 16 + fquad * 4 + r;
                float v = acc[i][jn][r] + bv;
                if (Cf) {
                    if (resid) v += resid[(size_t)row * N + col];
                    Cf[(size_t)row * N + col] = v;
                } else {
                    C[(size_t)row * N + col] = f2b(v);
                }
            }
        }
    }
}

// ---------------------------------------------------------------------------
// RoPE apply (in place, bf16)
// ---------------------------------------------------------------------------
__global__ __launch_bounds__(256)
void rope_apply(u16* __restrict__ Qb, u16* __restrict__ KVb,
                const float* __restrict__ ct, const float* __restrict__ st) {
    int gid = blockIdx.x * 256 + threadIdx.x;
    int row = gid >> 6, d = gid & 63;
    const int nq = BB * SS * NHH;
    u16* p;
    int s;
    if (row < nq) {
        s = (row / NHH) % SS;
        p = Qb + (size_t)row * HDD;
    } else {
        int r2 = row - nq;
        s = (r2 / KVHH) % SS;
        p = KVb + (size_t)r2 * 256;
    }
    float c = ct[s * 64 + d], sn = st[s * 64 + d];
    float x0 = b2f(p[d]), x1 = b2f(p[d + 64]);
    p[d]      = f2b(x0 * c - x1 * sn);
    p[d + 64] = f2b(x1 * c + x0 * sn);
}

// ---------------------------------------------------------------------------
// V transpose: KV[b,s,kvh, 128+d] -> VT[(b*KVH+kvh), d, s]
// ---------------------------------------------------------------------------
__global__ __launch_bounds__(256)
void vt_kernel(const u16* __restrict__ KVb, u16* __restrict__ VT) {
    __shared__ u16 t[64 * 130];
    int bid = blockIdx.x;
    int bk = bid >> 5;            // b*KVH + kvh
    int s0 = (bid & 31) * 64;
    int b = bk >> 3, kvh = bk & 7;
    for (int idx = threadIdx.x; idx < 64 * 128; idx += 256) {
        int si = idx >> 7, d = idx & 127;
        t[si * 130 + d] =
            KVb[((size_t)((b * SS + s0 + si) * KVHH + kvh)) * 256 + 128 + d];
    }
    __syncthreads();
    for (int idx = threadIdx.x; idx < 64 * 128; idx += 256) {
        int d = idx >> 6, sj = idx & 63;
        VT[((size_t)(bk * HDD + d)) * SS + s0 + sj] = t[sj * 130 + d];
    }
}

// ---------------------------------------------------------------------------
// Fused causal GQA flash attention, v2:
//  - XOR-swizzled LDS staging (chunk c of row r stored at c^(r&7)) kills the
//    16-way ds_read_b128 bank conflicts that plain 256B/128B row strides had.
//  - Q tile staged into the sK|sVT region (freed before k-loop): LDS 64->50KB
//    so 3 blocks/CU instead of 2.
//  - Heavy q-tiles (qt=15) dispatched FIRST (blockIdx remap) to kill the
//    load-imbalance tail.
//  - P-write -> PV barrier replaced with s_waitcnt lgkmcnt(0) (intra-wave dep
//    only: each wave reads back only its own 32 P rows).
// ---------------------------------------------------------------------------
__global__ __launch_bounds__(256, 3)
void attn(const u16* __restrict__ Q, const u16* __restrict__ KV,
          const u16* __restrict__ VT, u16* __restrict__ CTX) {
    __shared__ u16 smem[25600];          // 50 KB
    u16* sK  = smem;                     // [64][128]  (k-loop)
    u16* sVT = smem + 8192;              // [128][64]  (k-loop)
    u16* sP  = smem + 16384;             // [128][72]
    // smem[0..16384) doubles as the 128x128 Q staging tile before the loop.

    const int tid = threadIdx.x;
    const int wave = tid >> 6, lane = tid & 63;
    const int frow = lane & 15, fquad = lane >> 4;
    const int bid = blockIdx.x;
    const int qt = 15 - (bid >> 6);      // heavy tiles first
    const int b = (bid >> 5) & 1;
    const int h = bid & 31;
    const int kvh = h >> 2;
    const int q0 = qt * 128;

    // ---- stage Q tile (128 rows x 128 d) into smem[0..16384), swizzled ----
    {
        const int srow4 = lane >> 4;
        const int chunk = lane & 15;
#pragma unroll
        for (int j = 0; j < 8; ++j) {
            int rb = (j * 4 + wave) * 4;
            int sc = chunk ^ ((rb + srow4) & 7);     // source-chunk swizzle
            gll16(Q + ((size_t)((b * SS + q0 + rb + srow4) * NHH + h)) * HDD + sc * 8,
                  &smem[rb * 128]);
        }
    }
    __syncthreads();
    short8 qf[2][4];
#pragma unroll
    for (int mi = 0; mi < 2; ++mi)
#pragma unroll
        for (int ds = 0; ds < 4; ++ds)
            qf[mi][ds] = *(const short8*)
                &smem[(wave * 32 + mi * 16 + frow) * 128 +
                      ((ds * 4 + fquad) ^ (frow & 7)) * 8];
    __syncthreads();   // qf reads done before loop staging overwrites smem

    const floatx4 fz = {0.f, 0.f, 0.f, 0.f};
    floatx4 o[2][8];
#pragma unroll
    for (int mi = 0; mi < 2; ++mi)
#pragma unroll
        for (int dn = 0; dn < 8; ++dn) o[mi][dn] = fz;
    float mrow[2][4], lrow[2][4];
#pragma unroll
    for (int mi = 0; mi < 2; ++mi)
#pragma unroll
        for (int r = 0; r < 4; ++r) { mrow[mi][r] = -1e30f; lrow[mi][r] = 0.f; }

    const float scale = 0.08838834764831845f;  // 1/sqrt(128)
    const int nt = 2 * (qt + 1);
    for (int t = 0; t < nt; ++t) {
        const int k0 = t * 64;
        // ---- stage K (64x128) and VT (128x64), swizzled ----
        {
            const int srow4 = lane >> 4, ch16 = lane & 15;
#pragma unroll
            for (int j = 0; j < 4; ++j) {
                int rb = (j * 4 + wave) * 4;
                int sc = ch16 ^ ((rb + srow4) & 7);
                gll16(KV + ((size_t)((b * SS + k0 + rb + srow4) * KVHH + kvh)) * 256 + sc * 8,
                      &sK[rb * 128]);
            }
            const int srow8 = lane >> 3, ch8 = lane & 7;
#pragma unroll
            for (int j = 0; j < 4; ++j) {
                int rb = (j * 4 + wave) * 8;
                int sc = ch8 ^ ((rb + srow8) & 7);
                gll16(VT + ((size_t)((b * KVHH + kvh) * HDD + rb + srow8)) * SS + k0 + sc * 8,
                      &sVT[rb * 64]);
            }
        }
        __syncthreads();

        // ---- S = Q K^T : per wave 32 MFMAs ----
        floatx4 sc[2][4];
#pragma unroll
        for (int mi = 0; mi < 2; ++mi)
#pragma unroll
            for (int ni = 0; ni < 4; ++ni) sc[mi][ni] = fz;
#pragma unroll
        for (int ds = 0; ds < 4; ++ds) {
#pragma unroll
            for (int ni = 0; ni < 4; ++ni) {
                short8 kf = *(const short8*)
                    &sK[(ni * 16 + frow) * 128 +
                        ((ds * 4 + fquad) ^ (frow & 7)) * 8];
                sc[0][ni] = __builtin_amdgcn_mfma_f32_16x16x32_bf16(
                    qf[0][ds], kf, sc[0][ni], 0, 0, 0);
                sc[1][ni] = __builtin_amdgcn_mfma_f32_16x16x32_bf16(
                    qf[1][ds], kf, sc[1][ni], 0, 0, 0);
            }
        }

        // ---- online softmax ----
        const bool dgt = (t >= 2 * qt);  // diagonal tile needs element mask
#pragma unroll
        for (int mi = 0; mi < 2; ++mi) {
#pragma unroll
            for (int r = 0; r < 4; ++r) {
                int qg = q0 + wave * 32 + mi * 16 + fquad * 4 + r;
                float mx = -1e30f;
#pragma unroll
                for (int ni = 0; ni < 4; ++ni) {
                    float v = sc[mi][ni][r] * scale;
                    if (dgt) {
                        int kg = k0 + ni * 16 + frow;
                        if (kg > qg) v = -1e30f;
                    }
                    sc[mi][ni][r] = v;
                    mx = fmaxf(mx, v);
                }
                mx = fmaxf(mx, __shfl_xor(mx, 1));
                mx = fmaxf(mx, __shfl_xor(mx, 2));
                mx = fmaxf(mx, __shfl_xor(mx, 4));
                mx = fmaxf(mx, __shfl_xor(mx, 8));
                float mold = mrow[mi][r];
                float mnew = fmaxf(mold, mx);
                float alpha = __expf(mold - mnew);
                mrow[mi][r] = mnew;
                float rs = 0.f;
#pragma unroll
                for (int ni = 0; ni < 4; ++ni) {
                    float pv = __expf(sc[mi][ni][r] - mnew);
                    sc[mi][ni][r] = pv;
                    rs += pv;
                }
                rs += __shfl_xor(rs, 1);
                rs += __shfl_xor(rs, 2);
                rs += __shfl_xor(rs, 4);
                rs += __shfl_xor(rs, 8);
                lrow[mi][r] = lrow[mi][r] * alpha + rs;
#pragma unroll
                for (int dn = 0; dn < 8; ++dn) o[mi][dn][r] *= alpha;
            }
        }

        // ---- P -> LDS (bf16, stride 72); intra-wave consumer only ----
#pragma unroll
        for (int mi = 0; mi < 2; ++mi)
#pragma unroll
            for (int ni = 0; ni < 4; ++ni)
#pragma unroll
                for (int r = 0; r < 4; ++r)
                    sP[(wave * 32 + mi * 16 + fquad * 4 + r) * 72 + ni * 16 + frow] =
                        f2b(sc[mi][ni][r]);
        asm volatile("s_waitcnt lgkmcnt(0)" ::: "memory");

        // ---- O += P V : per wave 32 MFMAs ----
#pragma unroll
        for (int ks = 0; ks < 2; ++ks) {
            short8 pf0 = *(const short8*)
                &sP[(wave * 32 + frow) * 72 + ks * 32 + fquad * 8];
            short8 pf1 = *(const short8*)
                &sP[(wave * 32 + 16 + frow) * 72 + ks * 32 + fquad * 8];
#pragma unroll
            for (int dn = 0; dn < 8; ++dn) {
                short8 vf = *(const short8*)
                    &sVT[(dn * 16 + frow) * 64 +
                         ((ks * 4 + fquad) ^ (frow & 7)) * 8];
                o[0][dn] = __builtin_amdgcn_mfma_f32_16x16x32_bf16(pf0, vf, o[0][dn], 0, 0, 0);
                o[1][dn] = __builtin_amdgcn_mfma_f32_16x16x32_bf16(pf1, vf, o[1][dn], 0, 0, 0);
            }
        }
        __syncthreads();  // before next staging overwrites sK/sVT/sP
    }

    // ---- epilogue: ctx = O / l ----
#pragma unroll
    for (int mi = 0; mi < 2; ++mi) {
#pragma unroll
        for (int r = 0; r < 4; ++r) {
            float inv = 1.f / lrow[mi][r];
            int qg = q0 + wave * 32 + mi * 16 + fquad * 4 + r;
            size_t base = ((size_t)(b * SS + qg) * NHH + h) * HDD;
#pragma unroll
            for (int dn = 0; dn < 8; ++dn)
                CTX[base + dn * 16 + frow] = f2b(o[mi][dn][r] * inv);
        }
    }
}

// ---------------------------------------------------------------------------
// Launch. ws layout (121 MB total):
//   [0,32M) hsb | [32,64M) Qb/CTX | [64,80M) KVb | [80,112M) T1 |
//   [112,120M) VTb | [120,121M) cos/sin
// ---------------------------------------------------------------------------
extern "C" void kernel_launch(void* const* d_in, const int* in_sizes, int n_in,
                              void* d_out, int out_size, void* d_ws, size_t ws_size,
                              hipStream_t stream) {
    const float* hidden = (const float*)d_in[0];
    const float* resid  = (const float*)d_in[1];
    // d_in[2] = attention_mask (causal triu k=1) — reconstructed analytically
    const float* Wq  = (const float*)d_in[3];
    const float* Wkv = (const float*)d_in[4];
    const float* Wd  = (const float*)d_in[5];
    const float* bd  = (const float*)d_in[6];
    float* out = (float*)d_out;

    char* ws = (char*)d_ws;
    u16*   hsb = (u16*)(ws);
    u16*   Qb  = (u16*)(ws + ((size_t)32 << 20));
    u16*   KVb = (u16*)(ws + ((size_t)64 << 20));
    u16*   T1  = (u16*)(ws + ((size_t)80 << 20));
    u16*   VTb = (u16*)(ws + ((size_t)112 << 20));
    float* ct  = (float*)(ws + ((size_t)120 << 20));
    float* st  = (float*)(ws + ((size_t)120 << 20) + ((size_t)512 << 10));

    const int M = BB * SS;  // 4096

    rope_table<<<512, 256, 0, stream>>>(ct, st);
    cvt_kernel<<<(M * HH / 4 + 255) / 256, 256, 0, stream>>>(hidden, hsb, M * HH / 4);

    wt_kernel<<<4096, 256, 0, stream>>>(Wq, T1, HH, HH);
    gemm_bt<<<dim3(32, 32), 256, 0, stream>>>(hsb, T1, Qb, nullptr, M, HH, HH,
                                              nullptr, nullptr);
    wt_kernel<<<2048, 256, 0, stream>>>(Wkv, T1, HH, 2 * KVHH * HDD);
    gemm_bt<<<dim3(16, 32), 256, 0, stream>>>(hsb, T1, KVb, nullptr,
                                              M, 2 * KVHH * HDD, HH,
                                              nullptr, nullptr);

    rope_apply<<<(BB * SS * (NHH + KVHH) * 64) / 256, 256, 0, stream>>>(Qb, KVb, ct, st);
    vt_kernel<<<BB * KVHH * (SS / 64), 256, 0, stream>>>(KVb, VTb);

    attn<<<BB * 16 * NHH, 256, 0, stream>>>(Qb, KVb, VTb, /*CTX=*/Qb);

    wt_kernel<<<4096, 256, 0, stream>>>(Wd, T1, HH, HH);
    gemm_bt<<<dim3(32, 32), 256, 0, stream>>>(Qb, T1, nullptr, out, M, HH, HH,
                                              bd, resid);
}